// Round 1
// baseline (8400.318 us; speedup 1.0000x reference)
//
#include <hip/hip_runtime.h>

#define N_SRC0   286000
#define N_DST0   11000
#define N_E0     275000
#define N_DST1   1000
#define N_E1     10000
#define IN_FEATS 602
#define N_HIDDEN 256
#define N_CLASSES 41

// -------- CSR build: count, scan, fill --------

__global__ void count_kernel(const int* __restrict__ d0, int n0, int* __restrict__ c0,
                             const int* __restrict__ d1, int n1, int* __restrict__ c1) {
    int i = blockIdx.x * blockDim.x + threadIdx.x;
    if (i < n0) {
        atomicAdd(&c0[d0[i]], 1);
    } else {
        int j = i - n0;
        if (j < n1) atomicAdd(&c1[d1[j]], 1);
    }
}

// One block per segment array; block 0 scans layer-0 counts, block 1 layer-1.
__global__ void scan_kernel(const int* __restrict__ cnt0, int* __restrict__ off0, int n0_,
                            const int* __restrict__ cnt1, int* __restrict__ off1, int n1_) {
    const int* cnt; int* off; int n;
    if (blockIdx.x == 0) { cnt = cnt0; off = off0; n = n0_; }
    else                 { cnt = cnt1; off = off1; n = n1_; }
    __shared__ int sums[1024];
    int tid = threadIdx.x;
    int chunk = (n + 1023) >> 10;
    int start = tid * chunk;
    int end = min(start + chunk, n);
    int s = 0;
    for (int i = start; i < end; i++) s += cnt[i];
    sums[tid] = s;
    __syncthreads();
    // Hillis-Steele inclusive scan over the 1024 partial sums
    for (int d = 1; d < 1024; d <<= 1) {
        int v = (tid >= d) ? sums[tid - d] : 0;
        __syncthreads();
        sums[tid] += v;
        __syncthreads();
    }
    int run = (tid > 0) ? sums[tid - 1] : 0;
    for (int i = start; i < end; i++) { off[i] = run; run += cnt[i]; }
    if (tid == 1023) off[n] = run;
}

__global__ void fill_kernel(const int* __restrict__ s0, const int* __restrict__ d0, int n0,
                            const int* __restrict__ off0, int* __restrict__ cur0, int* __restrict__ csr0,
                            const int* __restrict__ s1, const int* __restrict__ d1, int n1,
                            const int* __restrict__ off1, int* __restrict__ cur1, int* __restrict__ csr1) {
    int i = blockIdx.x * blockDim.x + threadIdx.x;
    if (i < n0) {
        int d = d0[i];
        int p = atomicAdd(&cur0[d], 1);
        csr0[off0[d] + p] = s0[i];
    } else {
        int j = i - n0;
        if (j < n1) {
            int d = d1[j];
            int p = atomicAdd(&cur1[d], 1);
            csr1[off1[d] + p] = s1[j];
        }
    }
}

// -------- Layer-0 mean aggregation: one block per dst row --------
// 256 threads cover 602 feature columns (3 strided cols per thread).
__global__ void agg0_kernel(const float* __restrict__ x, const int* __restrict__ off,
                            const int* __restrict__ csr, float* __restrict__ agg) {
    int d = blockIdx.x;
    int tid = threadIdx.x;
    int c0 = tid, c1 = tid + 256, c2 = tid + 512;
    bool has2 = (c2 < IN_FEATS);
    float a0 = 0.f, a1 = 0.f, a2 = 0.f;
    int beg = off[d], end = off[d + 1];
    int e = beg;
    // 2x unroll for memory-level parallelism on the random row gathers
    for (; e + 1 < end; e += 2) {
        const float* r0 = x + (size_t)csr[e] * IN_FEATS;
        const float* r1 = x + (size_t)csr[e + 1] * IN_FEATS;
        float t00 = r0[c0], t01 = r0[c1];
        float t10 = r1[c0], t11 = r1[c1];
        float t02 = has2 ? r0[c2] : 0.f;
        float t12 = has2 ? r1[c2] : 0.f;
        a0 += t00 + t10;
        a1 += t01 + t11;
        a2 += t02 + t12;
    }
    if (e < end) {
        const float* r0 = x + (size_t)csr[e] * IN_FEATS;
        a0 += r0[c0];
        a1 += r0[c1];
        if (has2) a2 += r0[c2];
    }
    float inv = 1.f / fmaxf((float)(end - beg), 1.f);
    float* o = agg + (size_t)d * IN_FEATS;
    o[c0] = a0 * inv;
    o[c1] = a1 * inv;
    if (has2) o[c2] = a2 * inv;
}

// -------- Layer 0: h = relu(x[:N_DST0] @ Wself0 + agg @ Wneigh0 + b0) --------
// Block = 256 threads = 256 output cols; each block does BM0 rows.
// K loop runs over both (A, W) pairs: (x, Wself0) then (agg, Wneigh0).
#define BM0 32
__global__ void layer0_kernel(const float* __restrict__ x, const float* __restrict__ agg,
                              const float* __restrict__ Wself, const float* __restrict__ Wneigh,
                              const float* __restrict__ b, float* __restrict__ h) {
    int row0 = blockIdx.x * BM0;
    int tid = threadIdx.x;
    float acc[BM0];
#pragma unroll
    for (int r = 0; r < BM0; r++) acc[r] = 0.f;
    __shared__ float As[BM0][32];  // broadcast reads -> no bank conflicts
    for (int part = 0; part < 2; part++) {
        const float* A = part ? agg : x;
        const float* W = part ? Wneigh : Wself;
        for (int k0 = 0; k0 < IN_FEATS; k0 += 32) {
            __syncthreads();
            for (int i = tid; i < BM0 * 32; i += 256) {
                int r = i >> 5, k = i & 31;
                int gr = row0 + r;
                int kg = k0 + k;
                As[r][k] = (kg < IN_FEATS && gr < N_DST0) ? A[(size_t)gr * IN_FEATS + kg] : 0.f;
            }
            __syncthreads();
#pragma unroll
            for (int kk = 0; kk < 32; kk += 4) {
                int kg = k0 + kk;
                float w0 = (kg + 0 < IN_FEATS) ? W[(kg + 0) * N_HIDDEN + tid] : 0.f;
                float w1 = (kg + 1 < IN_FEATS) ? W[(kg + 1) * N_HIDDEN + tid] : 0.f;
                float w2 = (kg + 2 < IN_FEATS) ? W[(kg + 2) * N_HIDDEN + tid] : 0.f;
                float w3 = (kg + 3 < IN_FEATS) ? W[(kg + 3) * N_HIDDEN + tid] : 0.f;
#pragma unroll
                for (int r = 0; r < BM0; r++) {
                    float4 a = *(const float4*)&As[r][kk];
                    acc[r] += a.x * w0 + a.y * w1 + a.z * w2 + a.w * w3;
                }
            }
        }
    }
    float bias = b[tid];
#pragma unroll
    for (int r = 0; r < BM0; r++) {
        int gr = row0 + r;
        if (gr < N_DST0) h[(size_t)gr * N_HIDDEN + tid] = fmaxf(acc[r] + bias, 0.f);
    }
}

// -------- Layer-1 mean aggregation over h (256-dim): one block per dst --------
__global__ void agg1_kernel(const float* __restrict__ h, const int* __restrict__ off,
                            const int* __restrict__ csr, float* __restrict__ agg) {
    int d = blockIdx.x;
    int tid = threadIdx.x;
    float a = 0.f;
    int beg = off[d], end = off[d + 1];
    for (int e = beg; e < end; e++)
        a += h[(size_t)csr[e] * N_HIDDEN + tid];
    agg[(size_t)d * N_HIDDEN + tid] = a / fmaxf((float)(end - beg), 1.f);
}

// -------- Layer 1: out = h[:N_DST1] @ Wself1 + agg1 @ Wneigh1 + b1 --------
__global__ void layer1_kernel(const float* __restrict__ h, const float* __restrict__ agg1,
                              const float* __restrict__ Wself, const float* __restrict__ Wneigh,
                              const float* __restrict__ b, float* __restrict__ out) {
    int idx = blockIdx.x * blockDim.x + threadIdx.x;
    if (idx >= N_DST1 * N_CLASSES) return;
    int d = idx / N_CLASSES, c = idx % N_CLASSES;
    const float* hd = h + (size_t)d * N_HIDDEN;
    const float* ha = agg1 + (size_t)d * N_HIDDEN;
    float acc = b[c];
    for (int k = 0; k < N_HIDDEN; k++)
        acc += hd[k] * Wself[k * N_CLASSES + c] + ha[k] * Wneigh[k * N_CLASSES + c];
    out[idx] = acc;
}

extern "C" void kernel_launch(void* const* d_in, const int* in_sizes, int n_in,
                              void* d_out, int out_size, void* d_ws, size_t ws_size,
                              hipStream_t stream) {
    const float* x       = (const float*)d_in[0];
    const float* Wself0  = (const float*)d_in[1];
    const float* Wneigh0 = (const float*)d_in[2];
    const float* b0      = (const float*)d_in[3];
    const float* Wself1  = (const float*)d_in[4];
    const float* Wneigh1 = (const float*)d_in[5];
    const float* b1      = (const float*)d_in[6];
    const int* e0_src = (const int*)d_in[7];
    const int* e0_dst = (const int*)d_in[8];
    const int* e1_src = (const int*)d_in[9];
    const int* e1_dst = (const int*)d_in[10];

    // workspace layout (256B aligned slices)
    char* ws = (char*)d_ws;
    size_t o = 0;
    auto alloc = [&](size_t bytes) -> void* {
        void* p = ws + o;
        o = (o + bytes + 255) & ~(size_t)255;
        return p;
    };
    // counters block first (single memset covers cnt0|cur0|cnt1|cur1)
    int* cnt_block = (int*)alloc((size_t)(N_DST0 + N_DST0 + N_DST1 + N_DST1) * sizeof(int));
    int* cnt0 = cnt_block;
    int* cur0 = cnt_block + N_DST0;
    int* cnt1 = cnt_block + 2 * N_DST0;
    int* cur1 = cnt_block + 2 * N_DST0 + N_DST1;
    int* off0 = (int*)alloc((size_t)(N_DST0 + 1) * sizeof(int));
    int* off1 = (int*)alloc((size_t)(N_DST1 + 1) * sizeof(int));
    int* csr0 = (int*)alloc((size_t)N_E0 * sizeof(int));
    int* csr1 = (int*)alloc((size_t)N_E1 * sizeof(int));
    float* agg0 = (float*)alloc((size_t)N_DST0 * IN_FEATS * sizeof(float));
    float* h    = (float*)alloc((size_t)N_DST0 * N_HIDDEN * sizeof(float));
    float* agg1 = (float*)alloc((size_t)N_DST1 * N_HIDDEN * sizeof(float));

    hipMemsetAsync(cnt_block, 0, (size_t)(2 * N_DST0 + 2 * N_DST1) * sizeof(int), stream);

    int total_e = N_E0 + N_E1;
    count_kernel<<<(total_e + 255) / 256, 256, 0, stream>>>(e0_dst, N_E0, cnt0, e1_dst, N_E1, cnt1);
    scan_kernel<<<2, 1024, 0, stream>>>(cnt0, off0, N_DST0, cnt1, off1, N_DST1);
    fill_kernel<<<(total_e + 255) / 256, 256, 0, stream>>>(e0_src, e0_dst, N_E0, off0, cur0, csr0,
                                                           e1_src, e1_dst, N_E1, off1, cur1, csr1);
    agg0_kernel<<<N_DST0, 256, 0, stream>>>(x, off0, csr0, agg0);
    layer0_kernel<<<(N_DST0 + BM0 - 1) / BM0, 256, 0, stream>>>(x, agg0, Wself0, Wneigh0, b0, h);
    agg1_kernel<<<N_DST1, 256, 0, stream>>>(h, off1, csr1, agg1);
    layer1_kernel<<<(N_DST1 * N_CLASSES + 255) / 256, 256, 0, stream>>>(h, agg1, Wself1, Wneigh1, b1,
                                                                        (float*)d_out);
}

// Round 2
// 1194.602 us; speedup vs baseline: 7.0319x; 7.0319x over previous
//
#include <hip/hip_runtime.h>

#define N_SRC0   286000
#define N_DST0   11000
#define N_E0     275000
#define N_DST1   1000
#define N_E1     10000
#define IN_FEATS 602
#define N_HIDDEN 256
#define N_CLASSES 41

// -------- CSR build: count, scan, fill --------

__global__ void count_kernel(const int* __restrict__ d0, int n0, int* __restrict__ c0,
                             const int* __restrict__ d1, int n1, int* __restrict__ c1) {
    int i = blockIdx.x * blockDim.x + threadIdx.x;
    if (i < n0) {
        atomicAdd(&c0[d0[i]], 1);
    } else {
        int j = i - n0;
        if (j < n1) atomicAdd(&c1[d1[j]], 1);
    }
}

// One block per segment array; block 0 scans layer-0 counts, block 1 layer-1.
__global__ void scan_kernel(const int* __restrict__ cnt0, int* __restrict__ off0, int n0_,
                            const int* __restrict__ cnt1, int* __restrict__ off1, int n1_) {
    const int* cnt; int* off; int n;
    if (blockIdx.x == 0) { cnt = cnt0; off = off0; n = n0_; }
    else                 { cnt = cnt1; off = off1; n = n1_; }
    __shared__ int sums[1024];
    int tid = threadIdx.x;
    int chunk = (n + 1023) >> 10;
    int start = tid * chunk;
    int end = min(start + chunk, n);
    int s = 0;
    for (int i = start; i < end; i++) s += cnt[i];
    sums[tid] = s;
    __syncthreads();
    for (int d = 1; d < 1024; d <<= 1) {
        int v = (tid >= d) ? sums[tid - d] : 0;
        __syncthreads();
        sums[tid] += v;
        __syncthreads();
    }
    int run = (tid > 0) ? sums[tid - 1] : 0;
    for (int i = start; i < end; i++) { off[i] = run; run += cnt[i]; }
    if (tid == 1023) off[n] = run;
}

__global__ void fill_kernel(const int* __restrict__ s0, const int* __restrict__ d0, int n0,
                            const int* __restrict__ off0, int* __restrict__ cur0, int* __restrict__ csr0,
                            const int* __restrict__ s1, const int* __restrict__ d1, int n1,
                            const int* __restrict__ off1, int* __restrict__ cur1, int* __restrict__ csr1) {
    int i = blockIdx.x * blockDim.x + threadIdx.x;
    if (i < n0) {
        int d = d0[i];
        int p = atomicAdd(&cur0[d], 1);
        csr0[off0[d] + p] = s0[i];
    } else {
        int j = i - n0;
        if (j < n1) {
            int d = d1[j];
            int p = atomicAdd(&cur1[d], 1);
            csr1[off1[d] + p] = s1[j];
        }
    }
}

// -------- Layer-0 mean aggregation: one block per dst row --------
__global__ void agg0_kernel(const float* __restrict__ x, const int* __restrict__ off,
                            const int* __restrict__ csr, float* __restrict__ agg) {
    int d = blockIdx.x;
    int tid = threadIdx.x;
    int c0 = tid, c1 = tid + 256, c2 = tid + 512;
    bool has2 = (c2 < IN_FEATS);
    float a0 = 0.f, a1 = 0.f, a2 = 0.f;
    int beg = off[d], end = off[d + 1];
    int e = beg;
    for (; e + 1 < end; e += 2) {
        const float* r0 = x + (size_t)csr[e] * IN_FEATS;
        const float* r1 = x + (size_t)csr[e + 1] * IN_FEATS;
        float t00 = r0[c0], t01 = r0[c1];
        float t10 = r1[c0], t11 = r1[c1];
        float t02 = has2 ? r0[c2] : 0.f;
        float t12 = has2 ? r1[c2] : 0.f;
        a0 += t00 + t10;
        a1 += t01 + t11;
        a2 += t02 + t12;
    }
    if (e < end) {
        const float* r0 = x + (size_t)csr[e] * IN_FEATS;
        a0 += r0[c0];
        a1 += r0[c1];
        if (has2) a2 += r0[c2];
    }
    float inv = 1.f / fmaxf((float)(end - beg), 1.f);
    float* o = agg + (size_t)d * IN_FEATS;
    o[c0] = a0 * inv;
    o[c1] = a1 * inv;
    if (has2) o[c2] = a2 * inv;
}

// -------- Layer 0: h = relu(x[:N_DST0] @ Wself0 + agg @ Wneigh0 + b0) --------
// Classic register-blocked SGEMM: 64x64 tile per 256-thread block, 4x4
// accumulators per thread (16 VGPR acc + ~24 temps -> no spill; R1's BM=32
// per-thread-row scheme spilled acc[] to scratch -> 13 GB of scratch writes).
#define BM 64
#define BN 64
#define BK 16
#define TM 4
#define TN 4
#define LDA (BM + 4)   // +4 floats keeps 16B alignment for float4 LDS reads

__global__ __launch_bounds__(256) void layer0_kernel(
        const float* __restrict__ x, const float* __restrict__ agg,
        const float* __restrict__ Wself, const float* __restrict__ Wneigh,
        const float* __restrict__ b, float* __restrict__ h) {
    __shared__ float As[BK][LDA];  // A^T tile: As[k][m]
    __shared__ float Bs[BK][BN];   // B tile:   Bs[k][n]
    const int t  = threadIdx.x;
    const int tx = t & 15;   // N direction (4 cols each)
    const int ty = t >> 4;   // M direction (4 rows each)
    const int row0 = blockIdx.x * BM;
    const int col0 = blockIdx.y * BN;

    float acc[TM][TN];
#pragma unroll
    for (int m = 0; m < TM; m++)
#pragma unroll
        for (int n = 0; n < TN; n++) acc[m][n] = 0.f;

    for (int part = 0; part < 2; part++) {
        const float* A = part ? agg : x;
        const float* W = part ? Wneigh : Wself;
        for (int k0 = 0; k0 < IN_FEATS; k0 += BK) {
            // Stage A tile (64 rows x 16 k), transposed into As[k][m].
            // thread t, chunk l: linear idx -> (row i, k) ; consecutive t = consecutive k (coalesced 64B runs)
#pragma unroll
            for (int l = 0; l < (BM * BK) / 256; l++) {
                int idx = t + l * 256;
                int i = idx / BK, k = idx % BK;
                int gr = row0 + i, gk = k0 + k;
                As[k][i] = (gr < N_DST0 && gk < IN_FEATS) ? A[(size_t)gr * IN_FEATS + gk] : 0.f;
            }
            // Stage B tile (16 k x 64 n): fully coalesced rows of W.
#pragma unroll
            for (int l = 0; l < (BK * BN) / 256; l++) {
                int idx = t + l * 256;
                int k = idx / BN, n = idx % BN;
                int gk = k0 + k;
                Bs[k][n] = (gk < IN_FEATS) ? W[(size_t)gk * N_HIDDEN + col0 + n] : 0.f;
            }
            __syncthreads();
#pragma unroll
            for (int k = 0; k < BK; k++) {
                float4 av = *(const float4*)&As[k][ty * TM];  // 16B aligned (LDA*4 = 272B rows)
                float4 bv = *(const float4*)&Bs[k][tx * TN];  // 16B aligned (256B rows)
                float a[TM] = {av.x, av.y, av.z, av.w};
                float bb[TN] = {bv.x, bv.y, bv.z, bv.w};
#pragma unroll
                for (int m = 0; m < TM; m++)
#pragma unroll
                    for (int n = 0; n < TN; n++) acc[m][n] += a[m] * bb[n];
            }
            __syncthreads();
        }
    }
    // Epilogue: bias + ReLU, coalesced float stores.
#pragma unroll
    for (int m = 0; m < TM; m++) {
        int gr = row0 + ty * TM + m;
        if (gr < N_DST0) {
#pragma unroll
            for (int n = 0; n < TN; n++) {
                int gc = col0 + tx * TN + n;
                h[(size_t)gr * N_HIDDEN + gc] = fmaxf(acc[m][n] + b[gc], 0.f);
            }
        }
    }
}

// -------- Layer-1 mean aggregation over h (256-dim): one block per dst --------
__global__ void agg1_kernel(const float* __restrict__ h, const int* __restrict__ off,
                            const int* __restrict__ csr, float* __restrict__ agg) {
    int d = blockIdx.x;
    int tid = threadIdx.x;
    float a = 0.f;
    int beg = off[d], end = off[d + 1];
    for (int e = beg; e < end; e++)
        a += h[(size_t)csr[e] * N_HIDDEN + tid];
    agg[(size_t)d * N_HIDDEN + tid] = a / fmaxf((float)(end - beg), 1.f);
}

// -------- Layer 1: out = h[:N_DST1] @ Wself1 + agg1 @ Wneigh1 + b1 --------
__global__ void layer1_kernel(const float* __restrict__ h, const float* __restrict__ agg1,
                              const float* __restrict__ Wself, const float* __restrict__ Wneigh,
                              const float* __restrict__ b, float* __restrict__ out) {
    int idx = blockIdx.x * blockDim.x + threadIdx.x;
    if (idx >= N_DST1 * N_CLASSES) return;
    int d = idx / N_CLASSES, c = idx % N_CLASSES;
    const float* hd = h + (size_t)d * N_HIDDEN;
    const float* ha = agg1 + (size_t)d * N_HIDDEN;
    float acc = b[c];
    for (int k = 0; k < N_HIDDEN; k++)
        acc += hd[k] * Wself[k * N_CLASSES + c] + ha[k] * Wneigh[k * N_CLASSES + c];
    out[idx] = acc;
}

extern "C" void kernel_launch(void* const* d_in, const int* in_sizes, int n_in,
                              void* d_out, int out_size, void* d_ws, size_t ws_size,
                              hipStream_t stream) {
    const float* x       = (const float*)d_in[0];
    const float* Wself0  = (const float*)d_in[1];
    const float* Wneigh0 = (const float*)d_in[2];
    const float* b0      = (const float*)d_in[3];
    const float* Wself1  = (const float*)d_in[4];
    const float* Wneigh1 = (const float*)d_in[5];
    const float* b1      = (const float*)d_in[6];
    const int* e0_src = (const int*)d_in[7];
    const int* e0_dst = (const int*)d_in[8];
    const int* e1_src = (const int*)d_in[9];
    const int* e1_dst = (const int*)d_in[10];

    char* ws = (char*)d_ws;
    size_t o = 0;
    auto alloc = [&](size_t bytes) -> void* {
        void* p = ws + o;
        o = (o + bytes + 255) & ~(size_t)255;
        return p;
    };
    int* cnt_block = (int*)alloc((size_t)(N_DST0 + N_DST0 + N_DST1 + N_DST1) * sizeof(int));
    int* cnt0 = cnt_block;
    int* cur0 = cnt_block + N_DST0;
    int* cnt1 = cnt_block + 2 * N_DST0;
    int* cur1 = cnt_block + 2 * N_DST0 + N_DST1;
    int* off0 = (int*)alloc((size_t)(N_DST0 + 1) * sizeof(int));
    int* off1 = (int*)alloc((size_t)(N_DST1 + 1) * sizeof(int));
    int* csr0 = (int*)alloc((size_t)N_E0 * sizeof(int));
    int* csr1 = (int*)alloc((size_t)N_E1 * sizeof(int));
    float* agg0 = (float*)alloc((size_t)N_DST0 * IN_FEATS * sizeof(float));
    float* h    = (float*)alloc((size_t)N_DST0 * N_HIDDEN * sizeof(float));
    float* agg1 = (float*)alloc((size_t)N_DST1 * N_HIDDEN * sizeof(float));

    hipMemsetAsync(cnt_block, 0, (size_t)(2 * N_DST0 + 2 * N_DST1) * sizeof(int), stream);

    int total_e = N_E0 + N_E1;
    count_kernel<<<(total_e + 255) / 256, 256, 0, stream>>>(e0_dst, N_E0, cnt0, e1_dst, N_E1, cnt1);
    scan_kernel<<<2, 1024, 0, stream>>>(cnt0, off0, N_DST0, cnt1, off1, N_DST1);
    fill_kernel<<<(total_e + 255) / 256, 256, 0, stream>>>(e0_src, e0_dst, N_E0, off0, cur0, csr0,
                                                           e1_src, e1_dst, N_E1, off1, cur1, csr1);
    agg0_kernel<<<N_DST0, 256, 0, stream>>>(x, off0, csr0, agg0);
    dim3 g0((N_DST0 + BM - 1) / BM, N_HIDDEN / BN);
    layer0_kernel<<<g0, 256, 0, stream>>>(x, agg0, Wself0, Wneigh0, b0, h);
    agg1_kernel<<<N_DST1, 256, 0, stream>>>(h, off1, csr1, agg1);
    layer1_kernel<<<(N_DST1 * N_CLASSES + 255) / 256, 256, 0, stream>>>(h, agg1, Wself1, Wneigh1, b1,
                                                                        (float*)d_out);
}